// Round 10
// baseline (157.390 us; speedup 1.0000x reference)
//
#include <hip/hip_runtime.h>
#include <cstdint>
#include <cstddef>

#define BATCH 64
#define NIN   1024
#define CIN   256
#define NC    32
#define NP0   16     // colsum partials (k_convert grid x)
#define NPF   8      // k_fused j-blocks per batch (128 j each, 2 sub-tiles)
#define T_EPS 1e-7f
#define CT_S  72     // cT row stride in u16 (144 B)

typedef __attribute__((ext_vector_type(8))) short short8;   // 8 bf16 = 4 VGPR
typedef __attribute__((ext_vector_type(4))) float floatx4;  // MFMA 16x16 acc

__device__ __forceinline__ unsigned short bf16rne(float f) {
  unsigned int u = __float_as_uint(f);
  u += 0x7FFFu + ((u >> 16) & 1u);
  return (unsigned short)(u >> 16);
}
__device__ __forceinline__ float bf2f(unsigned short h) {
  return __uint_as_float(((unsigned int)h) << 16);
}
// swizzled u16 index into the 64x256 LDS x-tile (16B chunks XOR-permuted per j)
__device__ __forceinline__ int xsw(int j, int c) {
  return j * 256 + ((((c >> 3) ^ (j & 7) ^ ((j >> 3) & 7)) << 3) | (c & 7));
}

// ---- K1: x fp32 -> bf16 row-major + colsum partials + Wi build (b==0) ----
// grid (16, 64). Wi[i][c][k] bf16 = W[c][i*32+k].
__global__ __launch_bounds__(256) void k_convert(const float* __restrict__ x,
                                                 const float* __restrict__ W,
                                                 unsigned short* __restrict__ xb,
                                                 unsigned short* __restrict__ Wi,
                                                 float* __restrict__ y0p) {
  const int jc = blockIdx.x, b = blockIdx.y, t = threadIdx.x;
  const int jj = t >> 6, c4 = t & 63;
  __shared__ float4 red[4][64];
  const float4* xg = (const float4*)(x + ((size_t)(b * NIN + jc * 64)) * CIN);
  ushort4* xo = (ushort4*)(xb + ((size_t)(b * NIN + jc * 64)) * CIN);
  float4 acc = make_float4(0.f, 0.f, 0.f, 0.f);
  #pragma unroll
  for (int jr = 0; jr < 16; ++jr) {
    int j = jr * 4 + jj;
    float4 v = xg[j * 64 + c4];
    acc.x += v.x; acc.y += v.y; acc.z += v.z; acc.w += v.w;
    ushort4 h;
    h.x = bf16rne(v.x); h.y = bf16rne(v.y);
    h.z = bf16rne(v.z); h.w = bf16rne(v.w);
    xo[j * 64 + c4] = h;
  }
  red[jj][c4] = acc;
  if (b == 0) {
    #pragma unroll
    for (int i2 = 0; i2 < 2; ++i2) {
      int i = jc * 2 + i2;
      const float4* wsrc = (const float4*)(W + (size_t)t * 1024 + i * 32);
      unsigned short* wdst = Wi + ((size_t)i * CIN + t) * NC;
      #pragma unroll
      for (int k4 = 0; k4 < 8; ++k4) {
        float4 v = wsrc[k4];
        ushort4 h;
        h.x = bf16rne(v.x); h.y = bf16rne(v.y);
        h.z = bf16rne(v.z); h.w = bf16rne(v.w);
        *(ushort4*)&wdst[k4 * 4] = h;
      }
    }
  }
  __syncthreads();
  if (t < 64) {
    float4 s = red[0][t];
    #pragma unroll
    for (int p = 1; p < 4; ++p) {
      s.x += red[p][t].x; s.y += red[p][t].y;
      s.z += red[p][t].z; s.w += red[p][t].w;
    }
    *(float4*)&y0p[(b * NP0 + jc) * CIN + t * 4] = s;
  }
}

// ---- K2: y-reduce -> s = y@W_i -> squash -> wt(bf16) or out --------------
// grid (i=NC, b=BATCH). MODE 0: yin=y0p fp32 (NP0 partials, scale 1/32).
// MODE 1: yin=ypart bf16 [b][NPF][i][c], write wt. MODE 2: write out.
template <int MODE>
__global__ __launch_bounds__(256) void k_post(const void* __restrict__ yin,
                                              const unsigned short* __restrict__ Wi,
                                              unsigned short* __restrict__ wtout,
                                              float* __restrict__ outg) {
  const int i = blockIdx.x, b = blockIdx.y, t = threadIdx.x;
  __shared__ float ys[CIN];
  __shared__ float sred[8][32];
  __shared__ float os[NC];
  float a = 0.f;
  if (MODE == 0) {
    const float* y0p = (const float*)yin;
    #pragma unroll
    for (int p = 0; p < NP0; ++p) a += y0p[(b * NP0 + p) * CIN + t];
    a *= (1.f / 32.f);
  } else {
    const unsigned short* yp = (const unsigned short*)yin;
    #pragma unroll
    for (int p = 0; p < NPF; ++p)
      a += bf2f(yp[(((size_t)(b * NPF + p)) * NC + i) * CIN + t]);
  }
  ys[t] = a;
  __syncthreads();
  const unsigned short* Wis = Wi + (size_t)i * CIN * NC;
  {
    const int k = t & 31, g = t >> 5;
    float ps = 0.f;
    #pragma unroll
    for (int cc = 0; cc < 32; ++cc) {
      int c = g * 32 + ((cc + g * 4) & 31);
      ps += ys[c] * bf2f(Wis[c * NC + k]);
    }
    sred[g][k] = ps;
  }
  __syncthreads();
  const int k = t & 31;
  float s = 0.f;
  #pragma unroll
  for (int g = 0; g < 8; ++g) s += sred[g][k];
  float s2 = s * s;
  #pragma unroll
  for (int m = 1; m < 32; m <<= 1) s2 += __shfl_xor(s2, m);
  float o = s * rsqrtf(s2 + T_EPS);
  if (MODE == 2) {
    if (t < 32) outg[((size_t)b * NC + i) * 32 + t] = o;
  } else {
    if (t < 32) os[t] = o;
    __syncthreads();
    float acc = 0.f;
    const short8* wrow = (const short8*)(Wis + (size_t)t * NC);
    #pragma unroll
    for (int k8 = 0; k8 < 4; ++k8) {
      short8 wv = wrow[k8];
      #pragma unroll
      for (int e = 0; e < 8; ++e)
        acc += os[k8 * 8 + e] * bf2f((unsigned short)wv[e]);
    }
    wtout[((size_t)b * NC + i) * CIN + t] = bf16rne(acc);
  }
}

// ---- K3: MFMA-fused, 128 j per block via two 64-j sub-tiles --------------
// grid (NPF=8, 64), 4 waves. accB accumulates across both sub-tiles.
// Phase-B xf gather hoisted before the cT barrier (overlaps softmax VALU).
__global__ __launch_bounds__(256, 3) void k_fused(const unsigned short* __restrict__ xb,
                                                  const unsigned short* __restrict__ wt,
                                                  unsigned short* __restrict__ ypart) {
  const int jc = blockIdx.x, b = blockIdx.y, t = threadIdx.x;
  const int w = t >> 6, l16 = t & 15, q = (t >> 4) & 3;
  __shared__ unsigned short xs[64 * 256];    // 32 KB, swizzled
  __shared__ unsigned short cT[NC * CT_S];   // 4.6 KB
  const int jloc = w * 16 + l16;
  const int cw = w * 64;
  const unsigned short* wrow = wt + (size_t)b * NC * CIN;
  floatx4 accB[2][4];
  #pragma unroll
  for (int h = 0; h < 2; ++h)
    #pragma unroll
    for (int ct = 0; ct < 4; ++ct) accB[h][ct] = (floatx4){0.f, 0.f, 0.f, 0.f};

  #pragma unroll
  for (int sub = 0; sub < 2; ++sub) {
    __syncthreads();   // xs/cT free (previous sub's readers done)
    {  // stage 64x256 bf16 sub-tile (rows jc*128 + sub*64 ..+63)
      const short8* xg = (const short8*)(
          xb + ((size_t)(b * NIN) + (size_t)jc * 128 + sub * 64) * CIN);
      #pragma unroll
      for (int it = 0; it < 8; ++it) {
        int f = it * 256 + t;               // 0..2047 16B chunks
        int j = f >> 5, ch = f & 31;
        *(short8*)&xs[xsw(j, ch * 8)] = xg[f];
      }
    }
    __syncthreads();
    // phase A: logits over c=256 (8 K-steps of 32)
    floatx4 accA0 = {0.f, 0.f, 0.f, 0.f}, accA1 = {0.f, 0.f, 0.f, 0.f};
    #pragma unroll
    for (int ks = 0; ks < 8; ++ks) {
      short8 bx = *(const short8*)&xs[xsw(jloc, ks * 32 + q * 8)];
      short8 a0 = *(const short8*)(wrow + (size_t)l16 * CIN + ks * 32 + q * 8);
      short8 a1 = *(const short8*)(wrow + (size_t)(16 + l16) * CIN + ks * 32 + q * 8);
      accA0 = __builtin_amdgcn_mfma_f32_16x16x32_bf16(a0, bx, accA0, 0, 0, 0);
      accA1 = __builtin_amdgcn_mfma_f32_16x16x32_bf16(a1, bx, accA1, 0, 0, 0);
    }
    // pre-barrier phase-B x^T gather (independent of softmax/cT)
    short8 xf[2][4];
    #pragma unroll
    for (int ks = 0; ks < 2; ++ks)
      #pragma unroll
      for (int ct = 0; ct < 4; ++ct) {
        const int c = cw + ct * 16 + l16;
        #pragma unroll
        for (int e = 0; e < 8; ++e)
          xf[ks][ct][e] = (short)xs[xsw(ks * 32 + q * 8 + e, c)];
      }
    {  // softmax over i=32 for column j=jloc
      float m = accA0[0];
      #pragma unroll
      for (int r = 1; r < 4; ++r) m = fmaxf(m, accA0[r]);
      #pragma unroll
      for (int r = 0; r < 4; ++r) m = fmaxf(m, accA1[r]);
      m = fmaxf(m, __shfl_xor(m, 16));
      m = fmaxf(m, __shfl_xor(m, 32));
      float e0[4], e1[4], s = 0.f;
      #pragma unroll
      for (int r = 0; r < 4; ++r) {
        e0[r] = __expf(accA0[r] - m);
        e1[r] = __expf(accA1[r] - m);
        s += e0[r] + e1[r];
      }
      s += __shfl_xor(s, 16);
      s += __shfl_xor(s, 32);
      float rs = 1.f / s;
      #pragma unroll
      for (int r = 0; r < 4; ++r) {
        cT[(q * 4 + r) * CT_S + jloc]      = bf16rne(e0[r] * rs);
        cT[(16 + q * 4 + r) * CT_S + jloc] = bf16rne(e1[r] * rs);
      }
    }
    __syncthreads();   // cT complete
    // phase B: y[i, cw..+63] += sum_j c[i,j] x[j,c]
    #pragma unroll
    for (int ks = 0; ks < 2; ++ks) {
      short8 ca0 = *(const short8*)&cT[l16 * CT_S + ks * 32 + q * 8];
      short8 ca1 = *(const short8*)&cT[(16 + l16) * CT_S + ks * 32 + q * 8];
      #pragma unroll
      for (int ct = 0; ct < 4; ++ct) {
        accB[0][ct] = __builtin_amdgcn_mfma_f32_16x16x32_bf16(ca0, xf[ks][ct], accB[0][ct], 0, 0, 0);
        accB[1][ct] = __builtin_amdgcn_mfma_f32_16x16x32_bf16(ca1, xf[ks][ct], accB[1][ct], 0, 0, 0);
      }
    }
  }
  // epilogue: bf16 partial y, layout [b][NPF][i][c]
  unsigned short* yo = ypart + ((size_t)(b * NPF + jc)) * NC * CIN;
  #pragma unroll
  for (int h = 0; h < 2; ++h)
    #pragma unroll
    for (int ct = 0; ct < 4; ++ct)
      #pragma unroll
      for (int r = 0; r < 4; ++r) {
        int i = h * 16 + q * 4 + r;
        int c = cw + ct * 16 + l16;
        yo[i * CIN + c] = bf16rne(accB[h][ct][r]);
      }
}

extern "C" void kernel_launch(void* const* d_in, const int* in_sizes, int n_in,
                              void* d_out, int out_size, void* d_ws, size_t ws_size,
                              hipStream_t stream) {
  (void)in_sizes; (void)n_in; (void)out_size; (void)ws_size;
  const float* x = (const float*)d_in[0];
  const float* W = (const float*)d_in[1];
  float* out = (float*)d_out;
  char* ws = (char*)d_ws;
  // ws: xb 32MiB | wt 1MiB | ypart 8.4MiB | y0p 1MiB | Wi 512KiB
  unsigned short* xbuf  = (unsigned short*)ws;
  unsigned short* wtb   = (unsigned short*)(ws + (32ull << 20));
  unsigned short* ypart = (unsigned short*)(ws + (33ull << 20));
  float*          y0p   = (float*)(ws + (43ull << 20));
  unsigned short* Wi    = (unsigned short*)(ws + (44ull << 20));

  dim3 gconv(NP0, BATCH);     // (16, 64)
  dim3 gfuse(NPF, BATCH);     // (8, 64)
  dim3 gpost(NC, BATCH);      // (32, 64)
  k_convert<<<gconv, 256, 0, stream>>>(x, W, xbuf, Wi, y0p);
  k_post<0><<<gpost, 256, 0, stream>>>(y0p, Wi, wtb, nullptr);    // iter 0
  k_fused<<<gfuse, 256, 0, stream>>>(xbuf, wtb, ypart);           // iter 1
  k_post<1><<<gpost, 256, 0, stream>>>(ypart, Wi, wtb, nullptr);
  k_fused<<<gfuse, 256, 0, stream>>>(xbuf, wtb, ypart);           // iter 2
  k_post<2><<<gpost, 256, 0, stream>>>(ypart, Wi, nullptr, out);
}